// Round 2
// baseline (2771.389 us; speedup 1.0000x reference)
//
#include <hip/hip_runtime.h>
#include <hip/hip_bf16.h>
#include <math.h>

#define SEQ    1024
#define EMB    512
#define HID    512
#define G4     2048   // 4*HID
#define NBLK   32     // worker blocks (one unit-block each)
#define NCAND  512    // candidate blocks launched (workers elected from these)
#define UPB    16     // hidden units per worker block
#define NSLOT  4      // rotating h slots (WAR-safe at distance 4)

typedef unsigned long long u64;

// ---------------------------------------------------------------------------
// Phase A: x_gates[t][r] = dot(emb[tok[t]], w_ih[r]) + b_ih[r] + b_hh[r]
// 64x64 tile, K-chunks of 64, 4x4 micro-tile per thread.  (UNCHANGED —
// arithmetic order must stay bit-identical.)
// ---------------------------------------------------------------------------
__global__ __launch_bounds__(256) void xgates_kernel(
    const int* __restrict__ tok, const float* __restrict__ emb,
    const float* __restrict__ w_ih, const float* __restrict__ b_ih,
    const float* __restrict__ b_hh, float* __restrict__ xg)
{
  __shared__ float xs[64][68];   // +4 pad breaks power-of-2 bank stride
  __shared__ float wsh[64][68];
  __shared__ int   tok_s[64];

  const int tid = threadIdx.x;
  const int r0  = (int)blockIdx.x * 64;   // gate-row tile
  const int t0  = (int)blockIdx.y * 64;   // seq tile

  if (tid < 64) tok_s[tid] = tok[t0 + tid];
  __syncthreads();

  const int tx = tid & 15;   // r micro
  const int ty = tid >> 4;   // t micro

  float acc[4][4];
#pragma unroll
  for (int i = 0; i < 4; ++i)
#pragma unroll
    for (int j = 0; j < 4; ++j) acc[i][j] = 0.f;

  for (int kc = 0; kc < EMB; kc += 64) {
#pragma unroll
    for (int it = 0; it < 4; ++it) {
      int id  = it * 256 + tid;    // 0..1023 float4 slots
      int row = id >> 4;           // 0..63
      int c4  = id & 15;           // 0..15
      float4 xv = *(const float4*)(emb + (size_t)tok_s[row] * EMB + kc + c4 * 4);
      *(float4*)&xs[row][c4 * 4] = xv;
      float4 wv = *(const float4*)(w_ih + (size_t)(r0 + row) * EMB + kc + c4 * 4);
      *(float4*)&wsh[row][c4 * 4] = wv;
    }
    __syncthreads();

#pragma unroll
    for (int k4 = 0; k4 < 16; ++k4) {
      float4 xv[4], wv[4];
#pragma unroll
      for (int i = 0; i < 4; ++i) xv[i] = *(const float4*)&xs[ty * 4 + i][k4 * 4];
#pragma unroll
      for (int j = 0; j < 4; ++j) wv[j] = *(const float4*)&wsh[tx * 4 + j][k4 * 4];
#pragma unroll
      for (int i = 0; i < 4; ++i)
#pragma unroll
        for (int j = 0; j < 4; ++j) {
          acc[i][j] += xv[i].x * wv[j].x + xv[i].y * wv[j].y
                     + xv[i].z * wv[j].z + xv[i].w * wv[j].w;
        }
    }
    __syncthreads();
  }

  const int rbase = r0 + tx * 4;
  float bias[4];
#pragma unroll
  for (int j = 0; j < 4; ++j) bias[j] = b_ih[rbase + j] + b_hh[rbase + j];

#pragma unroll
  for (int i = 0; i < 4; ++i) {
    int t = t0 + ty * 4 + i;
    float4 o;
    o.x = acc[i][0] + bias[0];
    o.y = acc[i][1] + bias[1];
    o.z = acc[i][2] + bias[2];
    o.w = acc[i][3] + bias[3];
    *(float4*)(xg + (size_t)t * G4 + rbase) = o;
  }
}

// ---------------------------------------------------------------------------
// Phase B: sequential LSTM scan.
//
// Round-2 structure: ONE working group of 32 blocks, all provably on ONE XCD.
//   - NCAND=512 candidate blocks are launched; each reads its physical XCD id
//     via s_getreg(HW_REG_XCC_ID) (HW-verified on gfx950).
//   - The globally-first block (atomic ticket 0) publishes its XCD as leader.
//   - The first 32 blocks on the leader XCD claim worker tickets
//     (ticket == unit-block id); all other candidates exit immediately.
//   - ~57 KB of LDS caps residency at <=2 blocks/CU, so the 32 workers sit on
//     distinct CUs of the leader XCD.
//
// h exchange is intra-XCD through the leader XCD's L2:
//   producer: plain global_store_dwordx2  -> local L2 (~150cy)
//   consumer: sc0 (L1-bypass) load        -> served by same L2 (~250cy RTT)
// The (tag<<32)|f32 word makes stale reads benign (single-copy-atomic 8B).
// Producers ALSO store agent-scope to hslot; consumers escalate to an
// agent-scope load every 8 failed fast polls.  So even if placement or sc0
// semantics differ from the model, the kernel degrades to the proven
// baseline protocol instead of hanging or corrupting.
// ---------------------------------------------------------------------------
__global__ __launch_bounds__(512) void lstm_scan_kernel(
    const float* __restrict__ xg, const float* __restrict__ w_hh,
    u64* hslot /* agent: [NSLOT][HID] */,
    u64* hfast /* leader-XCD L2: [NSLOT][HID] */,
    int* ctrl  /* [0]=global ticket, [1]=leader(xcc+1; 0=unset), [2]=leader tickets */)
{
  // h_lds is deliberately oversized (padding): 52 KB + 4 KB part_lds caps
  // occupancy at <=2 blocks/CU so elected workers occupy distinct CUs.
  __shared__ float h_lds[13312];        // only [0..511] used
  __shared__ float part_lds[2][8 * 64]; // double-buffered partials
  __shared__ int   s_role;

  const int tid = threadIdx.x;

  // ---- worker election (thread 0 of each candidate block) ----------------
  if (tid == 0) {
    unsigned xcc;
    asm volatile("s_getreg_b32 %0, hwreg(HW_REG_XCC_ID)" : "=s"(xcc));
    xcc &= 7u;
    int g = __hip_atomic_fetch_add(&ctrl[0], 1, __ATOMIC_RELAXED,
                                   __HIP_MEMORY_SCOPE_AGENT);
    if (g == 0) {
      __hip_atomic_store(&ctrl[1], (int)xcc + 1, __ATOMIC_RELAXED,
                         __HIP_MEMORY_SCOPE_AGENT);
    }
    int leader;
    do {
      leader = __hip_atomic_load(&ctrl[1], __ATOMIC_RELAXED,
                                 __HIP_MEMORY_SCOPE_AGENT);
    } while (leader == 0);
    leader -= 1;
    int role = -1;
    if ((int)xcc == leader) {
      int tkt = __hip_atomic_fetch_add(&ctrl[2], 1, __ATOMIC_RELAXED,
                                       __HIP_MEMORY_SCOPE_AGENT);
      if (tkt < NBLK) role = tkt;   // worker: unit-block id = ticket
    }
    s_role = role;
  }
  __syncthreads();
  const int ublk = s_role;
  if (ublk < 0) return;   // non-worker candidate: free the CU immediately

  const int w    = tid >> 6;            // wave id = k-segment
  const int l    = tid & 63;            // lane   = local gate row
  const int q    = l >> 4;              // gate type (i,f,g,o)
  const int jj   = l & 15;              // local hidden unit
  const int grow = q * HID + ublk * UPB + jj;  // global gate row

  // This thread's 64 w_hh weights -> VGPRs.
  float wreg[64];
  {
    const float* wp = w_hh + (size_t)grow * HID + w * 64;
#pragma unroll
    for (int k4 = 0; k4 < 16; ++k4) {
      float4 v = ((const float4*)wp)[k4];
      wreg[4 * k4 + 0] = v.x; wreg[4 * k4 + 1] = v.y;
      wreg[4 * k4 + 2] = v.z; wreg[4 * k4 + 3] = v.w;
    }
  }

  float c_reg = 0.f;                       // cell state (wave0 lanes 0..15)
  float xgv = (w == 0) ? xg[grow] : 0.f;   // x_gates[0][grow]

  for (int t = 0; t < SEQ; ++t) {
    // --- h arrival: fast L2-local poll with agent-scope escalation --------
    const u64* fsrc = hfast + (size_t)(t & (NSLOT - 1)) * HID + tid;
    const u64* ssrc = hslot + (size_t)(t & (NSLOT - 1)) * HID + tid;
    u64 word;
    int spins = 0;
    while (true) {
      // sc0 = L1 bypass; served by this XCD's L2 where same-XCD plain
      // stores land.  Stale tag -> retry (tag+payload travel together).
      asm volatile("global_load_dwordx2 %0, %1, off sc0\n\t"
                   "s_waitcnt vmcnt(0)"
                   : "=v"(word) : "v"(fsrc) : "memory");
      if ((unsigned)(word >> 32) == (unsigned)t) break;
      if (((++spins) & 7) == 0) {
        // fallback: the proven agent-scope path (chip coherence point)
        word = __hip_atomic_load(ssrc, __ATOMIC_RELAXED, __HIP_MEMORY_SCOPE_AGENT);
        if ((unsigned)(word >> 32) == (unsigned)t) break;
      }
    }
    h_lds[tid] = __uint_as_float((unsigned)(word & 0xffffffffu));
    // No barrier: wave w reads only h_lds[64w..64w+63], written by its own
    // lanes (lockstep within a wave; lgkmcnt orders the ds ops).

    const float*  hb  = &h_lds[w * 64];
    const float4* hb4 = (const float4*)hb;
    float p0 = 0.f, p1 = 0.f, p2 = 0.f, p3 = 0.f;
    // float4 LDS reads; per-accumulator add order identical to the scalar
    // version (ascending k within each p) -> bit-identical result.
#pragma unroll
    for (int k4 = 0; k4 < 4; ++k4) {
      float4 h0 = hb4[k4];
      float4 h1 = hb4[k4 + 4];
      float4 h2 = hb4[k4 + 8];
      float4 h3 = hb4[k4 + 12];
      p0 += wreg[4 * k4 + 0] * h0.x; p0 += wreg[4 * k4 + 1] * h0.y;
      p0 += wreg[4 * k4 + 2] * h0.z; p0 += wreg[4 * k4 + 3] * h0.w;
      p1 += wreg[16 + 4 * k4 + 0] * h1.x; p1 += wreg[16 + 4 * k4 + 1] * h1.y;
      p1 += wreg[16 + 4 * k4 + 2] * h1.z; p1 += wreg[16 + 4 * k4 + 3] * h1.w;
      p2 += wreg[32 + 4 * k4 + 0] * h2.x; p2 += wreg[32 + 4 * k4 + 1] * h2.y;
      p2 += wreg[32 + 4 * k4 + 2] * h2.z; p2 += wreg[32 + 4 * k4 + 3] * h2.w;
      p3 += wreg[48 + 4 * k4 + 0] * h3.x; p3 += wreg[48 + 4 * k4 + 1] * h3.y;
      p3 += wreg[48 + 4 * k4 + 2] * h3.z; p3 += wreg[48 + 4 * k4 + 3] * h3.w;
    }
    part_lds[t & 1][w * 64 + l] = (p0 + p1) + (p2 + p3);
    __syncthreads();   // the only barrier per step

    if (w == 0) {
      const float* pp = &part_lds[t & 1][0];
      float s = ((pp[l]       + pp[64 + l]) + (pp[128 + l] + pp[192 + l]))
              + ((pp[256 + l] + pp[320 + l]) + (pp[384 + l] + pp[448 + l]));
      float gv = s + xgv;

      // prefetch next step's xg (used next iteration -> latency hidden)
      int tn = (t + 1 < SEQ) ? (t + 1) : (SEQ - 1);
      xgv = xg[(size_t)tn * G4 + grow];

      // gather the 4 gate values for unit jj into lanes 0..15
      float gi = __shfl(gv, jj,      64);
      float gf = __shfl(gv, jj + 16, 64);
      float gg = __shfl(gv, jj + 32, 64);
      float go = __shfl(gv, jj + 48, 64);

      if (l < UPB) {
        const float LOG2E = 1.442695041f;
        float i_ = 1.f / (1.f + __builtin_exp2f(-LOG2E * gi));
        float f_ = 1.f / (1.f + __builtin_exp2f(-LOG2E * gf));
        float g_ = 2.f / (1.f + __builtin_exp2f(-2.f * LOG2E * gg)) - 1.f;
        float o_ = 1.f / (1.f + __builtin_exp2f(-LOG2E * go));
        c_reg = f_ * c_reg + i_ * g_;
        float hv = o_ * (2.f / (1.f + __builtin_exp2f(-2.f * LOG2E * c_reg)) - 1.f);
        u64 outw = ((u64)(unsigned)(t + 1) << 32) | (u64)__float_as_uint(hv);

        // FAST path first (critical): plain store -> local XCD L2.
        u64* fdst = hfast + (size_t)((t + 1) & (NSLOT - 1)) * HID + ublk * UPB + jj;
        asm volatile("global_store_dwordx2 %0, %1, off"
                     :: "v"(fdst), "v"(outw) : "memory");
        // Fallback + final-output path: agent scope (chip-visible).
        __hip_atomic_store(hslot + (size_t)((t + 1) & (NSLOT - 1)) * HID + ublk * UPB + jj,
                           outw, __ATOMIC_RELAXED, __HIP_MEMORY_SCOPE_AGENT);
      }
    }
  }
}

// ---------------------------------------------------------------------------
// Phase C: attn = sigmoid(h @ attn_w^T + attn_b) broadcast to (64,32,32);
// also emit x_instr_rep = h. h comes packed in hslot slot 0 (tag 1024).
// ---------------------------------------------------------------------------
__global__ __launch_bounds__(256) void head_kernel(
    const u64* __restrict__ hpacked, const float* __restrict__ attn_w,
    const float* __restrict__ attn_b, float* __restrict__ out)
{
  __shared__ float red[4];
  __shared__ float aval;
  const int r   = blockIdx.x;   // 0..63
  const int tid = threadIdx.x;

  float h0 = __uint_as_float((unsigned)(hpacked[tid]       & 0xffffffffu));
  float h1 = __uint_as_float((unsigned)(hpacked[256 + tid] & 0xffffffffu));

  float p = attn_w[(size_t)r * HID + tid] * h0
          + attn_w[(size_t)r * HID + 256 + tid] * h1;
#pragma unroll
  for (int off = 1; off < 64; off <<= 1) p += __shfl_xor(p, off, 64);
  if ((tid & 63) == 0) red[tid >> 6] = p;
  __syncthreads();
  if (tid == 0) {
    float sum = red[0] + red[1] + red[2] + red[3] + attn_b[r];
    aval = 1.f / (1.f + __expf(-sum));
  }
  __syncthreads();

  float a = aval;
  float4 av = make_float4(a, a, a, a);
  ((float4*)(out + (size_t)r * 1024))[tid] = av;   // 256*16B = 1024 floats

  if (r == 0) {   // x_instr_rep = h (512 floats) at offset 64*32*32
    out[65536 + tid]       = h0;
    out[65536 + 256 + tid] = h1;
  }
}

// ---------------------------------------------------------------------------
extern "C" void kernel_launch(void* const* d_in, const int* in_sizes, int n_in,
                              void* d_out, int out_size, void* d_ws, size_t ws_size,
                              hipStream_t stream) {
  const int*   tok    = (const int*)  d_in[0];
  const float* emb    = (const float*)d_in[1];
  const float* w_ih   = (const float*)d_in[2];
  const float* w_hh   = (const float*)d_in[3];
  const float* b_ih   = (const float*)d_in[4];
  const float* b_hh   = (const float*)d_in[5];
  const float* attn_w = (const float*)d_in[6];
  const float* attn_b = (const float*)d_in[7];
  float* out = (float*)d_out;

  char* ws = (char*)d_ws;
  float* xg    = (float*)ws;                              // 8 MB
  u64*   hslot = (u64*)(ws + (size_t)SEQ * G4 * 4);       // agent buf, 16 KB
  u64*   hfast = hslot + (size_t)NSLOT * HID;             // L2-local buf, 16 KB
  int*   ctrl  = (int*)(hfast + (size_t)NSLOT * HID);     // election, 64 B

  // ws is poisoned 0xAA before every launch: zero h slots (tag 0 == h^0=0)
  // and the election control words in one contiguous memset.
  hipMemsetAsync(hslot, 0, 2 * (size_t)NSLOT * HID * sizeof(u64) + 64, stream);

  dim3 gA(G4 / 64, SEQ / 64);   // 32 x 16 tiles
  xgates_kernel<<<gA, 256, 0, stream>>>(tok, emb, w_ih, b_ih, b_hh, xg);
  lstm_scan_kernel<<<NCAND, 512, 0, stream>>>(xg, w_hh, hslot, hfast, ctrl);
  // h^1024 lands in slot (1024 & 3) == 0.
  head_kernel<<<64, 256, 0, stream>>>(hslot, attn_w, attn_b, out);
}

// Round 3
// 2063.523 us; speedup vs baseline: 1.3430x; 1.3430x over previous
//
#include <hip/hip_runtime.h>
#include <hip/hip_bf16.h>
#include <math.h>

#define SEQ    1024
#define EMB    512
#define HID    512
#define G4     2048   // 4*HID
#define NBLK   32     // worker blocks (one unit-block each)
#define NCAND  512    // candidate blocks launched (workers elected from these)
#define UPB    16     // hidden units per worker block
#define NSLOT  4      // rotating h slots (WAR-safe at distance 4)

typedef unsigned long long u64;

// ---------------------------------------------------------------------------
// Phase A: x_gates[t][r] = dot(emb[tok[t]], w_ih[r]) + b_ih[r] + b_hh[r]
// 64x64 tile, K-chunks of 64, 4x4 micro-tile per thread.  (UNCHANGED —
// arithmetic order must stay bit-identical.)
// ---------------------------------------------------------------------------
__global__ __launch_bounds__(256) void xgates_kernel(
    const int* __restrict__ tok, const float* __restrict__ emb,
    const float* __restrict__ w_ih, const float* __restrict__ b_ih,
    const float* __restrict__ b_hh, float* __restrict__ xg)
{
  __shared__ float xs[64][68];   // +4 pad breaks power-of-2 bank stride
  __shared__ float wsh[64][68];
  __shared__ int   tok_s[64];

  const int tid = threadIdx.x;
  const int r0  = (int)blockIdx.x * 64;   // gate-row tile
  const int t0  = (int)blockIdx.y * 64;   // seq tile

  if (tid < 64) tok_s[tid] = tok[t0 + tid];
  __syncthreads();

  const int tx = tid & 15;   // r micro
  const int ty = tid >> 4;   // t micro

  float acc[4][4];
#pragma unroll
  for (int i = 0; i < 4; ++i)
#pragma unroll
    for (int j = 0; j < 4; ++j) acc[i][j] = 0.f;

  for (int kc = 0; kc < EMB; kc += 64) {
#pragma unroll
    for (int it = 0; it < 4; ++it) {
      int id  = it * 256 + tid;    // 0..1023 float4 slots
      int row = id >> 4;           // 0..63
      int c4  = id & 15;           // 0..15
      float4 xv = *(const float4*)(emb + (size_t)tok_s[row] * EMB + kc + c4 * 4);
      *(float4*)&xs[row][c4 * 4] = xv;
      float4 wv = *(const float4*)(w_ih + (size_t)(r0 + row) * EMB + kc + c4 * 4);
      *(float4*)&wsh[row][c4 * 4] = wv;
    }
    __syncthreads();

#pragma unroll
    for (int k4 = 0; k4 < 16; ++k4) {
      float4 xv[4], wv[4];
#pragma unroll
      for (int i = 0; i < 4; ++i) xv[i] = *(const float4*)&xs[ty * 4 + i][k4 * 4];
#pragma unroll
      for (int j = 0; j < 4; ++j) wv[j] = *(const float4*)&wsh[tx * 4 + j][k4 * 4];
#pragma unroll
      for (int i = 0; i < 4; ++i)
#pragma unroll
        for (int j = 0; j < 4; ++j) {
          acc[i][j] += xv[i].x * wv[j].x + xv[i].y * wv[j].y
                     + xv[i].z * wv[j].z + xv[i].w * wv[j].w;
        }
    }
    __syncthreads();
  }

  const int rbase = r0 + tx * 4;
  float bias[4];
#pragma unroll
  for (int j = 0; j < 4; ++j) bias[j] = b_ih[rbase + j] + b_hh[rbase + j];

#pragma unroll
  for (int i = 0; i < 4; ++i) {
    int t = t0 + ty * 4 + i;
    float4 o;
    o.x = acc[i][0] + bias[0];
    o.y = acc[i][1] + bias[1];
    o.z = acc[i][2] + bias[2];
    o.w = acc[i][3] + bias[3];
    *(float4*)(xg + (size_t)t * G4 + rbase) = o;
  }
}

// ---------------------------------------------------------------------------
// Phase B: sequential LSTM scan.
//
// Structure (validated in Round 2): ONE working group of 32 blocks, all
// provably on ONE XCD via XCC_ID election from 512 candidates; ~57 KB LDS
// caps residency so workers spread over the leader XCD's CUs; non-workers
// exit immediately.
//
// Round-3 fix: the producer's fast store now carries `sc0` (SE scope ->
// forced write-through to the XCD's L2).  Round 2's plain (CU-scope) store
// was never visible to the consumers' L2-scope polls (counters: detection
// always fell through to the agent fallback, +2400cy/step).  With both
// sides of the rendezvous at L2 scope, detect = one local-L2 RTT.
// Escalation to the proven agent-scope path now fires every 2 failed fast
// polls, so even if the fast path is dead the cadence ~= baseline.
// ---------------------------------------------------------------------------
__global__ __launch_bounds__(512) void lstm_scan_kernel(
    const float* __restrict__ xg, const float* __restrict__ w_hh,
    u64* hslot /* agent: [NSLOT][HID] */,
    u64* hfast /* leader-XCD L2: [NSLOT][HID] */,
    int* ctrl  /* [0]=global ticket, [1]=leader(xcc+1; 0=unset), [2]=leader tickets */)
{
  // h_lds is deliberately oversized (padding): 52 KB + 4 KB part_lds caps
  // occupancy at <=2 blocks/CU so elected workers spread across CUs.
  __shared__ float h_lds[13312];        // only [0..511] used
  __shared__ float part_lds[2][8 * 64]; // double-buffered partials
  __shared__ int   s_role;

  const int tid = threadIdx.x;

  // ---- worker election (thread 0 of each candidate block) ----------------
  if (tid == 0) {
    unsigned xcc;
    asm volatile("s_getreg_b32 %0, hwreg(HW_REG_XCC_ID)" : "=s"(xcc));
    xcc &= 7u;
    int g = __hip_atomic_fetch_add(&ctrl[0], 1, __ATOMIC_RELAXED,
                                   __HIP_MEMORY_SCOPE_AGENT);
    if (g == 0) {
      __hip_atomic_store(&ctrl[1], (int)xcc + 1, __ATOMIC_RELAXED,
                         __HIP_MEMORY_SCOPE_AGENT);
    }
    int leader;
    do {
      leader = __hip_atomic_load(&ctrl[1], __ATOMIC_RELAXED,
                                 __HIP_MEMORY_SCOPE_AGENT);
    } while (leader == 0);
    leader -= 1;
    int role = -1;
    if ((int)xcc == leader) {
      int tkt = __hip_atomic_fetch_add(&ctrl[2], 1, __ATOMIC_RELAXED,
                                       __HIP_MEMORY_SCOPE_AGENT);
      if (tkt < NBLK) role = tkt;   // worker: unit-block id = ticket
    }
    s_role = role;
  }
  __syncthreads();
  const int ublk = s_role;
  if (ublk < 0) return;   // non-worker candidate: free the CU immediately

  const int w    = tid >> 6;            // wave id = k-segment
  const int l    = tid & 63;            // lane   = local gate row
  const int q    = l >> 4;              // gate type (i,f,g,o)
  const int jj   = l & 15;              // local hidden unit
  const int grow = q * HID + ublk * UPB + jj;  // global gate row

  // This thread's 64 w_hh weights -> VGPRs.
  float wreg[64];
  {
    const float* wp = w_hh + (size_t)grow * HID + w * 64;
#pragma unroll
    for (int k4 = 0; k4 < 16; ++k4) {
      float4 v = ((const float4*)wp)[k4];
      wreg[4 * k4 + 0] = v.x; wreg[4 * k4 + 1] = v.y;
      wreg[4 * k4 + 2] = v.z; wreg[4 * k4 + 3] = v.w;
    }
  }

  float c_reg = 0.f;                       // cell state (wave0 lanes 0..15)
  float xgv = (w == 0) ? xg[grow] : 0.f;   // x_gates[0][grow]

  for (int t = 0; t < SEQ; ++t) {
    // --- h arrival: fast L2-local poll with agent-scope escalation --------
    const u64* fsrc = hfast + (size_t)(t & (NSLOT - 1)) * HID + tid;
    const u64* ssrc = hslot + (size_t)(t & (NSLOT - 1)) * HID + tid;
    u64 word;
    int spins = 0;
    while (true) {
      // sc0 load = L1 bypass, served by this XCD's L2 where the producers'
      // sc0 stores land.  Stale tag -> retry (tag+payload travel together
      // in one single-copy-atomic 8B word).
      asm volatile("global_load_dwordx2 %0, %1, off sc0\n\t"
                   "s_waitcnt vmcnt(0)"
                   : "=v"(word) : "v"(fsrc) : "memory");
      if ((unsigned)(word >> 32) == (unsigned)t) break;
      if (((++spins) & 1) == 0) {
        // fallback: the proven agent-scope path (chip coherence point)
        word = __hip_atomic_load(ssrc, __ATOMIC_RELAXED, __HIP_MEMORY_SCOPE_AGENT);
        if ((unsigned)(word >> 32) == (unsigned)t) break;
      }
    }
    h_lds[tid] = __uint_as_float((unsigned)(word & 0xffffffffu));
    // No barrier: wave w reads only h_lds[64w..64w+63], written by its own
    // lanes (lockstep within a wave; lgkmcnt orders the ds ops).

    const float*  hb  = &h_lds[w * 64];
    const float4* hb4 = (const float4*)hb;
    float p0 = 0.f, p1 = 0.f, p2 = 0.f, p3 = 0.f;
    // float4 LDS reads; per-accumulator add order identical to the scalar
    // version (ascending k within each p) -> bit-identical result.
#pragma unroll
    for (int k4 = 0; k4 < 4; ++k4) {
      float4 h0 = hb4[k4];
      float4 h1 = hb4[k4 + 4];
      float4 h2 = hb4[k4 + 8];
      float4 h3 = hb4[k4 + 12];
      p0 += wreg[4 * k4 + 0] * h0.x; p0 += wreg[4 * k4 + 1] * h0.y;
      p0 += wreg[4 * k4 + 2] * h0.z; p0 += wreg[4 * k4 + 3] * h0.w;
      p1 += wreg[16 + 4 * k4 + 0] * h1.x; p1 += wreg[16 + 4 * k4 + 1] * h1.y;
      p1 += wreg[16 + 4 * k4 + 2] * h1.z; p1 += wreg[16 + 4 * k4 + 3] * h1.w;
      p2 += wreg[32 + 4 * k4 + 0] * h2.x; p2 += wreg[32 + 4 * k4 + 1] * h2.y;
      p2 += wreg[32 + 4 * k4 + 2] * h2.z; p2 += wreg[32 + 4 * k4 + 3] * h2.w;
      p3 += wreg[48 + 4 * k4 + 0] * h3.x; p3 += wreg[48 + 4 * k4 + 1] * h3.y;
      p3 += wreg[48 + 4 * k4 + 2] * h3.z; p3 += wreg[48 + 4 * k4 + 3] * h3.w;
    }
    part_lds[t & 1][w * 64 + l] = (p0 + p1) + (p2 + p3);
    __syncthreads();   // the only barrier per step

    if (w == 0) {
      const float* pp = &part_lds[t & 1][0];
      float s = ((pp[l]       + pp[64 + l]) + (pp[128 + l] + pp[192 + l]))
              + ((pp[256 + l] + pp[320 + l]) + (pp[384 + l] + pp[448 + l]));
      float gv = s + xgv;

      // prefetch next step's xg (used next iteration -> latency hidden)
      int tn = (t + 1 < SEQ) ? (t + 1) : (SEQ - 1);
      xgv = xg[(size_t)tn * G4 + grow];

      // gather the 4 gate values for unit jj into lanes 0..15
      float gi = __shfl(gv, jj,      64);
      float gf = __shfl(gv, jj + 16, 64);
      float gg = __shfl(gv, jj + 32, 64);
      float go = __shfl(gv, jj + 48, 64);

      if (l < UPB) {
        const float LOG2E = 1.442695041f;
        float i_ = 1.f / (1.f + __builtin_exp2f(-LOG2E * gi));
        float f_ = 1.f / (1.f + __builtin_exp2f(-LOG2E * gf));
        float g_ = 2.f / (1.f + __builtin_exp2f(-2.f * LOG2E * gg)) - 1.f;
        float o_ = 1.f / (1.f + __builtin_exp2f(-LOG2E * go));
        c_reg = f_ * c_reg + i_ * g_;
        float hv = o_ * (2.f / (1.f + __builtin_exp2f(-2.f * LOG2E * c_reg)) - 1.f);
        u64 outw = ((u64)(unsigned)(t + 1) << 32) | (u64)__float_as_uint(hv);

        // FAST path first (critical): sc0 store -> write-through to the
        // local XCD L2 (Round 2's plain CU-scope store never left L1).
        u64* fdst = hfast + (size_t)((t + 1) & (NSLOT - 1)) * HID + ublk * UPB + jj;
        asm volatile("global_store_dwordx2 %0, %1, off sc0"
                     :: "v"(fdst), "v"(outw) : "memory");
        // Fallback + final-output path: agent scope (chip-visible).
        __hip_atomic_store(hslot + (size_t)((t + 1) & (NSLOT - 1)) * HID + ublk * UPB + jj,
                           outw, __ATOMIC_RELAXED, __HIP_MEMORY_SCOPE_AGENT);
      }
    }
  }
}

// ---------------------------------------------------------------------------
// Phase C: attn = sigmoid(h @ attn_w^T + attn_b) broadcast to (64,32,32);
// also emit x_instr_rep = h. h comes packed in hslot slot 0 (tag 1024).
// ---------------------------------------------------------------------------
__global__ __launch_bounds__(256) void head_kernel(
    const u64* __restrict__ hpacked, const float* __restrict__ attn_w,
    const float* __restrict__ attn_b, float* __restrict__ out)
{
  __shared__ float red[4];
  __shared__ float aval;
  const int r   = blockIdx.x;   // 0..63
  const int tid = threadIdx.x;

  float h0 = __uint_as_float((unsigned)(hpacked[tid]       & 0xffffffffu));
  float h1 = __uint_as_float((unsigned)(hpacked[256 + tid] & 0xffffffffu));

  float p = attn_w[(size_t)r * HID + tid] * h0
          + attn_w[(size_t)r * HID + 256 + tid] * h1;
#pragma unroll
  for (int off = 1; off < 64; off <<= 1) p += __shfl_xor(p, off, 64);
  if ((tid & 63) == 0) red[tid >> 6] = p;
  __syncthreads();
  if (tid == 0) {
    float sum = red[0] + red[1] + red[2] + red[3] + attn_b[r];
    aval = 1.f / (1.f + __expf(-sum));
  }
  __syncthreads();

  float a = aval;
  float4 av = make_float4(a, a, a, a);
  ((float4*)(out + (size_t)r * 1024))[tid] = av;   // 256*16B = 1024 floats

  if (r == 0) {   // x_instr_rep = h (512 floats) at offset 64*32*32
    out[65536 + tid]       = h0;
    out[65536 + 256 + tid] = h1;
  }
}

// ---------------------------------------------------------------------------
extern "C" void kernel_launch(void* const* d_in, const int* in_sizes, int n_in,
                              void* d_out, int out_size, void* d_ws, size_t ws_size,
                              hipStream_t stream) {
  const int*   tok    = (const int*)  d_in[0];
  const float* emb    = (const float*)d_in[1];
  const float* w_ih   = (const float*)d_in[2];
  const float* w_hh   = (const float*)d_in[3];
  const float* b_ih   = (const float*)d_in[4];
  const float* b_hh   = (const float*)d_in[5];
  const float* attn_w = (const float*)d_in[6];
  const float* attn_b = (const float*)d_in[7];
  float* out = (float*)d_out;

  char* ws = (char*)d_ws;
  float* xg    = (float*)ws;                              // 8 MB
  u64*   hslot = (u64*)(ws + (size_t)SEQ * G4 * 4);       // agent buf, 16 KB
  u64*   hfast = hslot + (size_t)NSLOT * HID;             // L2-local buf, 16 KB
  int*   ctrl  = (int*)(hfast + (size_t)NSLOT * HID);     // election, 64 B

  // ws is poisoned 0xAA before every launch: zero h slots (tag 0 == h^0=0)
  // and the election control words in one contiguous memset.
  hipMemsetAsync(hslot, 0, 2 * (size_t)NSLOT * HID * sizeof(u64) + 64, stream);

  dim3 gA(G4 / 64, SEQ / 64);   // 32 x 16 tiles
  xgates_kernel<<<gA, 256, 0, stream>>>(tok, emb, w_ih, b_ih, b_hh, xg);
  lstm_scan_kernel<<<NCAND, 512, 0, stream>>>(xg, w_hh, hslot, hfast, ctrl);
  // h^1024 lands in slot (1024 & 3) == 0.
  head_kernel<<<64, 256, 0, stream>>>(hslot, attn_w, attn_b, out);
}

// Round 6
// 1818.102 us; speedup vs baseline: 1.5243x; 1.1350x over previous
//
#include <hip/hip_runtime.h>
#include <hip/hip_bf16.h>
#include <math.h>

#define SEQ    1024
#define EMB    512
#define HID    512
#define G4     2048   // 4*HID
#define NBLK   32     // persistent scan blocks
#define UPB    16     // hidden units per scan block
#define NSLOT  4      // rotating h slots (WAR-safe at distance 4)

typedef unsigned long long u64;

// ---------------------------------------------------------------------------
// Phase A: x_gates[t][r] = dot(emb[tok[t]], w_ih[r]) + b_ih[r] + b_hh[r]
// 64x64 tile, K-chunks of 64, 4x4 micro-tile per thread.  (EXACT R0 version.)
// ---------------------------------------------------------------------------
__global__ __launch_bounds__(256) void xgates_kernel(
    const int* __restrict__ tok, const float* __restrict__ emb,
    const float* __restrict__ w_ih, const float* __restrict__ b_ih,
    const float* __restrict__ b_hh, float* __restrict__ xg)
{
  __shared__ float xs[64][68];   // +4 pad breaks power-of-2 bank stride
  __shared__ float wsh[64][68];
  __shared__ int   tok_s[64];

  const int tid = threadIdx.x;
  const int r0  = (int)blockIdx.x * 64;   // gate-row tile
  const int t0  = (int)blockIdx.y * 64;   // seq tile

  if (tid < 64) tok_s[tid] = tok[t0 + tid];
  __syncthreads();

  const int tx = tid & 15;   // r micro
  const int ty = tid >> 4;   // t micro

  float acc[4][4];
#pragma unroll
  for (int i = 0; i < 4; ++i)
#pragma unroll
    for (int j = 0; j < 4; ++j) acc[i][j] = 0.f;

  for (int kc = 0; kc < EMB; kc += 64) {
#pragma unroll
    for (int it = 0; it < 4; ++it) {
      int id  = it * 256 + tid;    // 0..1023 float4 slots
      int row = id >> 4;           // 0..63
      int c4  = id & 15;           // 0..15
      float4 xv = *(const float4*)(emb + (size_t)tok_s[row] * EMB + kc + c4 * 4);
      *(float4*)&xs[row][c4 * 4] = xv;
      float4 wv = *(const float4*)(w_ih + (size_t)(r0 + row) * EMB + kc + c4 * 4);
      *(float4*)&wsh[row][c4 * 4] = wv;
    }
    __syncthreads();

#pragma unroll
    for (int k4 = 0; k4 < 16; ++k4) {
      float4 xv[4], wv[4];
#pragma unroll
      for (int i = 0; i < 4; ++i) xv[i] = *(const float4*)&xs[ty * 4 + i][k4 * 4];
#pragma unroll
      for (int j = 0; j < 4; ++j) wv[j] = *(const float4*)&wsh[tx * 4 + j][k4 * 4];
#pragma unroll
      for (int i = 0; i < 4; ++i)
#pragma unroll
        for (int j = 0; j < 4; ++j) {
          acc[i][j] += xv[i].x * wv[j].x + xv[i].y * wv[j].y
                     + xv[i].z * wv[j].z + xv[i].w * wv[j].w;
        }
    }
    __syncthreads();
  }

  const int rbase = r0 + tx * 4;
  float bias[4];
#pragma unroll
  for (int j = 0; j < 4; ++j) bias[j] = b_ih[rbase + j] + b_hh[rbase + j];

#pragma unroll
  for (int i = 0; i < 4; ++i) {
    int t = t0 + ty * 4 + i;
    float4 o;
    o.x = acc[i][0] + bias[0];
    o.y = acc[i][1] + bias[1];
    o.z = acc[i][2] + bias[2];
    o.w = acc[i][3] + bias[3];
    *(float4*)(xg + (size_t)t * G4 + rbase) = o;
  }
}

// ---------------------------------------------------------------------------
// Phase B: sequential LSTM scan, 32 persistent blocks x 512 threads.
// EXACT R0 baseline protocol (proven 1570us): agent-scope tagged-word
// exchange, one barrier per step, epilogue xg prefetch.
//
// SINGLE Round-6 change: adaptive pre-poll sleep.  Serial polling detects h
// at (#misses)*RTT + RTT; the misses are phase-quantization waste (~2-3
// LLC RTTs/step at baseline).  Each wave sleeps a feedback-tuned duration
// before its FIRST poll so that poll lands just after h arrives.
//   feedback: any lane missed -> delay += 2 (fast recovery);
//             clean hit       -> delay -= 1 every 4th step (slow drift).
// Wave-uniform (branch conditions are __any/__all results), capped at 48
// units (~3072 cy) -> worst case is bounded slowdown, never a hang; the
// exchange protocol itself is untouched.
// ---------------------------------------------------------------------------
__global__ __launch_bounds__(512) void lstm_scan_kernel(
    const float* __restrict__ xg, const float* __restrict__ w_hh,
    u64* hslot /* [NSLOT][HID] */)
{
  __shared__ float h_lds[512];          // per-wave disjoint 64-float regions
  __shared__ float part_lds[2][8 * 64]; // double-buffered partials

  const int tid = threadIdx.x;
  const int blk = blockIdx.x;
  const int w   = tid >> 6;            // wave id = k-segment
  const int l   = tid & 63;            // lane   = local gate row
  const int q   = l >> 4;              // gate type (i,f,g,o)
  const int jj  = l & 15;              // local hidden unit
  const int grow = q * HID + blk * UPB + jj;  // global gate row

  // This thread's 64 w_hh weights -> VGPRs.
  float wreg[64];
  {
    const float* wp = w_hh + (size_t)grow * HID + w * 64;
#pragma unroll
    for (int k4 = 0; k4 < 16; ++k4) {
      float4 v = ((const float4*)wp)[k4];
      wreg[4 * k4 + 0] = v.x; wreg[4 * k4 + 1] = v.y;
      wreg[4 * k4 + 2] = v.z; wreg[4 * k4 + 3] = v.w;
    }
  }

  float c_reg = 0.f;                       // cell state (wave0 lanes 0..15)
  float xgv = (w == 0) ? xg[grow] : 0.f;   // x_gates[0][grow]
  int   delay = 0;                         // adaptive pre-poll sleep units

  for (int t = 0; t < SEQ; ++t) {
    // Adaptive pre-sleep: time the first poll to land just after h arrives.
#pragma unroll 1
    for (int i = 0; i < delay; ++i) __builtin_amdgcn_s_sleep(1);

    // Poll own h element: tag must equal t. Tag+payload in one atomic word.
    u64 word;
    int spins = 0;
    const u64* src = hslot + (size_t)(t & (NSLOT - 1)) * HID + tid;
    do {
      word = __hip_atomic_load(src, __ATOMIC_RELAXED, __HIP_MEMORY_SCOPE_AGENT);
      if ((unsigned)(word >> 32) == (unsigned)t) break;
      ++spins;
    } while (true);
    // Wave-uniform feedback (conditions are cross-lane reductions).
    if (__any(spins != 0))                   { if (delay < 48) delay += 2; }
    else if ((t & 3) == 0 && delay > 0)      { --delay; }

    h_lds[tid] = __uint_as_float((unsigned)(word & 0xffffffffu));
    // No barrier: wave w reads only h_lds[64w..64w+63], written by its own
    // lanes (lockstep within a wave; lgkmcnt orders the ds ops).

    const float* hb = &h_lds[w * 64];
    float p0 = 0.f, p1 = 0.f, p2 = 0.f, p3 = 0.f;
#pragma unroll
    for (int k = 0; k < 16; ++k) {
      p0 += wreg[k]      * hb[k];
      p1 += wreg[k + 16] * hb[k + 16];
      p2 += wreg[k + 32] * hb[k + 32];
      p3 += wreg[k + 48] * hb[k + 48];
    }
    part_lds[t & 1][w * 64 + l] = (p0 + p1) + (p2 + p3);
    __syncthreads();   // the only barrier per step

    if (w == 0) {
      const float* pp = &part_lds[t & 1][0];
      float s = ((pp[l]       + pp[64 + l]) + (pp[128 + l] + pp[192 + l]))
              + ((pp[256 + l] + pp[320 + l]) + (pp[384 + l] + pp[448 + l]));
      float gv = s + xgv;

      // prefetch next step's xg (used next iteration -> latency hidden)
      int tn = (t + 1 < SEQ) ? (t + 1) : (SEQ - 1);
      xgv = xg[(size_t)tn * G4 + grow];

      // gather the 4 gate values for unit jj into lanes 0..15
      float gi = __shfl(gv, jj,      64);
      float gf = __shfl(gv, jj + 16, 64);
      float gg = __shfl(gv, jj + 32, 64);
      float go = __shfl(gv, jj + 48, 64);

      if (l < UPB) {
        const float LOG2E = 1.442695041f;
        float i_ = 1.f / (1.f + __builtin_exp2f(-LOG2E * gi));
        float f_ = 1.f / (1.f + __builtin_exp2f(-LOG2E * gf));
        float g_ = 2.f / (1.f + __builtin_exp2f(-2.f * LOG2E * gg)) - 1.f;
        float o_ = 1.f / (1.f + __builtin_exp2f(-LOG2E * go));
        c_reg = f_ * c_reg + i_ * g_;
        float hv = o_ * (2.f / (1.f + __builtin_exp2f(-2.f * LOG2E * c_reg)) - 1.f);
        u64 outw = ((u64)(unsigned)(t + 1) << 32) | (u64)__float_as_uint(hv);
        __hip_atomic_store(hslot + (size_t)((t + 1) & (NSLOT - 1)) * HID + blk * UPB + jj,
                           outw, __ATOMIC_RELAXED, __HIP_MEMORY_SCOPE_AGENT);
      }
    }
  }
}

// ---------------------------------------------------------------------------
// Phase C: attn = sigmoid(h @ attn_w^T + attn_b) broadcast to (64,32,32);
// also emit x_instr_rep = h. h comes packed in hslot slot 0 (tag 1024).
// ---------------------------------------------------------------------------
__global__ __launch_bounds__(256) void head_kernel(
    const u64* __restrict__ hpacked, const float* __restrict__ attn_w,
    const float* __restrict__ attn_b, float* __restrict__ out)
{
  __shared__ float red[4];
  __shared__ float aval;
  const int r   = blockIdx.x;   // 0..63
  const int tid = threadIdx.x;

  float h0 = __uint_as_float((unsigned)(hpacked[tid]       & 0xffffffffu));
  float h1 = __uint_as_float((unsigned)(hpacked[256 + tid] & 0xffffffffu));

  float p = attn_w[(size_t)r * HID + tid] * h0
          + attn_w[(size_t)r * HID + 256 + tid] * h1;
#pragma unroll
  for (int off = 1; off < 64; off <<= 1) p += __shfl_xor(p, off, 64);
  if ((tid & 63) == 0) red[tid >> 6] = p;
  __syncthreads();
  if (tid == 0) {
    float sum = red[0] + red[1] + red[2] + red[3] + attn_b[r];
    aval = 1.f / (1.f + __expf(-sum));
  }
  __syncthreads();

  float a = aval;
  float4 av = make_float4(a, a, a, a);
  ((float4*)(out + (size_t)r * 1024))[tid] = av;   // 256*16B = 1024 floats

  if (r == 0) {   // x_instr_rep = h (512 floats) at offset 64*32*32
    out[65536 + tid]       = h0;
    out[65536 + 256 + tid] = h1;
  }
}

// ---------------------------------------------------------------------------
extern "C" void kernel_launch(void* const* d_in, const int* in_sizes, int n_in,
                              void* d_out, int out_size, void* d_ws, size_t ws_size,
                              hipStream_t stream) {
  const int*   tok    = (const int*)  d_in[0];
  const float* emb    = (const float*)d_in[1];
  const float* w_ih   = (const float*)d_in[2];
  const float* w_hh   = (const float*)d_in[3];
  const float* b_ih   = (const float*)d_in[4];
  const float* b_hh   = (const float*)d_in[5];
  const float* attn_w = (const float*)d_in[6];
  const float* attn_b = (const float*)d_in[7];
  float* out = (float*)d_out;

  char* ws = (char*)d_ws;
  float* xg    = (float*)ws;                              // 8 MB
  u64*   hslot = (u64*)(ws + (size_t)SEQ * G4 * 4);       // 4*512*8 = 16 KB

  // ws is poisoned 0xAA before every launch: zero the h slots (tag 0 == h^0=0).
  hipMemsetAsync(hslot, 0, NSLOT * HID * sizeof(u64), stream);

  dim3 gA(G4 / 64, SEQ / 64);   // 32 x 16 tiles
  xgates_kernel<<<gA, 256, 0, stream>>>(tok, emb, w_ih, b_ih, b_hh, xg);
  lstm_scan_kernel<<<NBLK, 512, 0, stream>>>(xg, w_hh, hslot);
  // h^1024 lands in slot (1024 & 3) == 0.
  head_kernel<<<64, 256, 0, stream>>>(hslot, attn_w, attn_b, out);
}